// Round 3
// baseline (1247.696 us; speedup 1.0000x reference)
//
#include <hip/hip_runtime.h>
#include <hip/hip_fp16.h>

#define D 64
#define NBUK 391      // ceil(100096/256) buckets of 256 nodes (key >> 8)
#define CAP 4608      // padded bucket capacity: mean 4096 + 8 sigma (64); graph fixed
#define NCH 12500     // per-wave chunks: N/8

// ---- scatter: edges -> padded buckets via global atomic cursors ----
// Replaces phase1+scanA+phase2: the cursor end-values ARE the histogram.
// Order within a bucket is arbitrary (finalize fine-sorts); fp-sum order
// noise ~1e-6 << fp16 quantization floor 2^-12.
__global__ __launch_bounds__(256) void scatter_kernel(const int* __restrict__ src,
                                                      const int* __restrict__ dst,
                                                      int* __restrict__ gdst,
                                                      int* __restrict__ gsrc,
                                                      int* __restrict__ pairs,
                                                      unsigned char* __restrict__ skeys, int E) {
    int stride = (int)gridDim.x * 1024;
    for (int k = ((int)blockIdx.x * 256 + (int)threadIdx.x) * 4; k < E; k += stride) {
        if (k + 3 < E) {
            int4 d4 = *(const int4*)(dst + k);
            int4 s4 = *(const int4*)(src + k);
#define PUT(dv, sv) { int b_ = (dv) >> 8; int p_ = atomicAdd(&gdst[b_], 1);                 \
                      if (p_ < CAP) pairs[(size_t)b_ * CAP + p_] = ((sv) << 8) | ((dv) & 255); \
                      int sb_ = (sv) >> 8; int q_ = atomicAdd(&gsrc[sb_], 1);               \
                      if (q_ < CAP) skeys[(size_t)sb_ * CAP + q_] = (unsigned char)((sv) & 255); }
            PUT(d4.x, s4.x) PUT(d4.y, s4.y) PUT(d4.z, s4.z) PUT(d4.w, s4.w)
        } else {
            for (int t = k; t < E && t < k + 4; ++t) { int dv = dst[t], sv = src[t]; PUT(dv, sv) }
#undef PUT
        }
    }
}

// ---- scan: exclusive-scan dst bucket counts; zero msum; init fused tickets ----
__global__ __launch_bounds__(512) void scan_kernel(const int* __restrict__ gdst,
                                                   int* __restrict__ cb_dst,
                                                   float* __restrict__ msum,
                                                   int* __restrict__ tick) {
    __shared__ int s[512];
    int tid = (int)threadIdx.x;
    if (tid < D) msum[tid] = 0.0f;
    if (tid < 3) tick[tid] = 768 * 4;     // first 3072 chunks pre-assigned to waves
    int v = (tid < NBUK) ? min(gdst[tid], CAP) : 0;
    s[tid] = v;
    __syncthreads();
    for (int off = 1; off < 512; off <<= 1) {
        int t = (tid >= off) ? s[tid - off] : 0;
        __syncthreads();
        s[tid] += t;
        __syncthreads();
    }
    if (tid < NBUK) cb_dst[tid] = s[tid] - v;
    if (tid == NBUK - 1) cb_dst[NBUK] = s[tid];
}

// ---- finalize: per bucket, dinv from src-keys; row_ptr + contiguous col from
//      padded dst-pairs; fused fp16 prescale of this bucket's feature rows ----
__global__ __launch_bounds__(256) void finalize_csr_kernel(const int* __restrict__ pairs,
                                                           const unsigned char* __restrict__ skeys,
                                                           const int* __restrict__ gdst,
                                                           const int* __restrict__ gsrc,
                                                           const int* __restrict__ cb_dst,
                                                           const float* __restrict__ feat,
                                                           int* __restrict__ row_ptr,
                                                           int* __restrict__ col,
                                                           float* __restrict__ dinv,
                                                           __half* __restrict__ hs, int N) {
    __shared__ int fine[256];
    __shared__ int lcur[256];
    __shared__ float dsh[256];
    __shared__ int wtot[4], wexcl[4];
    int b = (int)blockIdx.x;
    int tid = (int)threadIdx.x, lane = tid & 63, wv = tid >> 6;
    int g = b * 256 + tid;

    // out-degree -> dinv (src half, padded bucket)
    fine[tid] = 0;
    __syncthreads();
    size_t sb0 = (size_t)b * CAP;
    int scnt = min(gsrc[b], CAP);
    for (int i = tid; i < scnt; i += 256) atomicAdd(&fine[skeys[sb0 + i]], 1);
    __syncthreads();
    float dv_ = 1.0f / fmaxf((float)fine[tid], 1.0f);
    dsh[tid] = dv_;
    if (g < N) dinv[g] = dv_;
    __syncthreads();

    // prescale this bucket's rows: hs[node][:] = half(feat[node][:] * dinv[node])
    {
        int q = tid & 7;
        int rbase = tid >> 3;
        for (int p = 0; p < 8; ++p) {
            int r = p * 32 + rbase;
            int node = b * 256 + r;
            if (node < N) {
                float sc = dsh[r];
                const float4* f = (const float4*)(feat + (size_t)node * D + q * 8);
                float4 v0 = f[0], v1 = f[1];
                __half2 h[4];
                h[0] = __floats2half2_rn(v0.x * sc, v0.y * sc);
                h[1] = __floats2half2_rn(v0.z * sc, v0.w * sc);
                h[2] = __floats2half2_rn(v1.x * sc, v1.y * sc);
                h[3] = __floats2half2_rn(v1.z * sc, v1.w * sc);
                *(float4*)(hs + (size_t)node * D + q * 8) = *(float4*)h;
            }
        }
    }
    __syncthreads();

    // in-degree fine hist (dst half, padded bucket)
    fine[tid] = 0;
    __syncthreads();
    size_t pb = (size_t)b * CAP;
    int dcnt = min(gdst[b], CAP);
    for (int i = tid; i < dcnt; i += 256) atomicAdd(&fine[pairs[pb + i] & 255], 1);
    __syncthreads();
    int v = fine[tid], x = v;
#pragma unroll
    for (int d = 1; d < 64; d <<= 1) {
        int t = __shfl_up(x, d);
        if (lane >= d) x += t;
    }
    if (lane == 63) wtot[wv] = x;
    __syncthreads();
    if (tid == 0) {
        int a = 0;
#pragma unroll
        for (int k = 0; k < 4; ++k) { wexcl[k] = a; a += wtot[k]; }
    }
    __syncthreads();
    int cb0 = cb_dst[b];
    int excl = x - v + wexcl[wv];
    if (g <= N) row_ptr[g] = cb0 + excl;
    lcur[tid] = cb0 + excl;
    __syncthreads();
    for (int i = tid; i < dcnt; i += 256) {
        int p = pairs[pb + i];
        int pos = atomicAdd(&lcur[p & 255], 1);
        col[pos] = p >> 8;
    }
}

__device__ inline void accum8(float* a, float4 raw) {
    __half2* h = (__half2*)&raw;
#pragma unroll
    for (int k = 0; k < 4; ++k) {
        float2 f = __half22float2(h[k]);
        a[2 * k] += f.x;
        a[2 * k + 1] += f.y;
    }
}

// ---- fused gather(fp16) + GEMM (+ column-sum on final layer) ----
// R14. Gather core unchanged from R13 (8-deep register ring): three
// structurally different gathers (R0 VGPR 4-deep, R1 LDS-DMA pipelined,
// R2 VGPR 8-deep) all converge at 67+-5us => per-CU miss-concurrency cap
// (~17 lines in flight at ~430cy avg L2/L3 latency; Little's law from
// FETCH=83MB/205MB demand). Don't re-plumb the gather.
// NEW: per-WAVE chunk ownership + global ticket for tail balance (3125
// tiles/768 blocks = 4.07 rounds left a ~25% serial tail). All tile-loop
// LDS was already wave-private -> zero barriers; each wave grabs its next
// 8-row chunk via atomicAdd issued at gather-start (latency hidden).
// HARD RULE: grid == resident capacity = 768 @ launch_bounds(256,3).
__global__ __launch_bounds__(256, 3) void fused_kernel(const __half* __restrict__ hs_in,
                                                       const int* __restrict__ row_ptr,
                                                       const int* __restrict__ col,
                                                       const float* __restrict__ W,
                                                       const float* __restrict__ bias,
                                                       const float* __restrict__ dinv,
                                                       float* __restrict__ outf,
                                                       __half* __restrict__ outh,
                                                       float* __restrict__ msum,
                                                       int* __restrict__ tick,
                                                       int N, int mode) {
    __shared__ int colsh[2][4][384];    // [buf][wave][slot]
    __shared__ float aggT[4][8][68];    // [wave][row][d]
    __shared__ float red[256];
    int tid = (int)threadIdx.x;
    int lane = tid & 63;
    int wv = tid >> 6;
    int sg = lane >> 3;       // row-slot 0..7 within wave
    int q = lane & 7;         // 8 lanes per row, 16B (8 halves) each

    float Wreg[64];
#pragma unroll
    for (int k = 0; k < 64; ++k) Wreg[k] = W[k * 64 + lane];
    float breg = bias[lane];
    float colacc = 0.0f;

    int c = (int)blockIdx.x * 4 + wv;   // initial chunk: pre-assigned

    // ---- prologue: meta + colsh stage for first chunk ----
    int beg, deg, off, cnt;
    {
        int node = c * 8 + sg;
        beg = row_ptr[min(node, N)];
        int end = row_ptr[min(node + 1, N)];
        int cb = __shfl(beg, 0);        // lane 0: sg=0,q=0 -> row_ptr[c*8]
        int ce = __shfl(end, 56);       // lane 56: sg=7 -> row_ptr[c*8+8]
        cnt = ce - cb; off = beg - cb; deg = end - beg;
        if (cnt <= 384) {
#pragma unroll
            for (int k = 0; k < 6; ++k) {
                int i = k * 64 + lane;
                if (i < cnt) colsh[0][wv][i] = col[cb + i];
            }
        }
    }
    int p = 0;

    while (c < NCH) {
        int tkt = 0;
        if (lane == 0) tkt = atomicAdd(tick, 1);   // issue early; consumed post-gather

        int md = deg;                  // wave-max degree (groups on lane bits 3..5)
        md = max(md, __shfl_xor(md, 8));
        md = max(md, __shfl_xor(md, 16));
        md = max(md, __shfl_xor(md, 32));
        int rounds = (md + 3) >> 2;

        float a[8];
#pragma unroll
        for (int k = 0; k < 8; ++k) a[k] = 0.0f;

        if (cnt <= 384) {
            const int* cbuf = &colsh[p][wv][0];
            int cl = cnt - 1;          // clamp: overflow lanes dup last col -> 1 extra line, L1-hit
            float4 A0, A1, A2, A3, B0, B1, B2, B3;
#define LD1(dstv, e_) { int ci = min(off + (e_), cl); int srcn = cbuf[ci]; \
                        dstv = *(const float4*)(hs_in + (size_t)srcn * D + q * 8); }
#define ISS(X0, X1, X2, X3, b_) { int eb = (b_) << 2; \
        LD1(X0, eb) LD1(X1, eb + 1) LD1(X2, eb + 2) LD1(X3, eb + 3) }
#define CNS(X0, X1, X2, X3, b_) { int eb = (b_) << 2; \
        if (eb < deg) accum8(a, X0); if (eb + 1 < deg) accum8(a, X1); \
        if (eb + 2 < deg) accum8(a, X2); if (eb + 3 < deg) accum8(a, X3); }
            if (rounds > 0) {
                ISS(A0, A1, A2, A3, 0)
                if (rounds > 1) ISS(B0, B1, B2, B3, 1)
                int b = 0;
                while (true) {
                    CNS(A0, A1, A2, A3, b)
                    if (b + 2 < rounds) ISS(A0, A1, A2, A3, b + 2)
                    ++b; if (b >= rounds) break;
                    CNS(B0, B1, B2, B3, b)
                    if (b + 2 < rounds) ISS(B0, B1, B2, B3, b + 2)
                    ++b; if (b >= rounds) break;
                }
            }
#undef LD1
#undef ISS
#undef CNS
        } else {
            // safety fallback (cnt > 384 is ~+22 sigma for this graph)
            int end = beg + deg;
            for (int j = beg; j < end; ++j) {
                int s0 = col[j];
                float4 r0 = *(const float4*)(hs_in + (size_t)s0 * D + q * 8);
                accum8(a, r0);
            }
        }

        // ---- next chunk via ticket; stage meta + col values into REGS ----
        int c2 = __shfl(tkt, 0);
        bool hn = c2 < NCH;
        int beg2 = 0, deg2 = 0, off2 = 0, cnt2 = 0, cb2 = 0;
        if (hn) {
            int node2 = c2 * 8 + sg;
            beg2 = row_ptr[min(node2, N)];
            int end2 = row_ptr[min(node2 + 1, N)];
            cb2 = __shfl(beg2, 0);
            int ce2 = __shfl(end2, 56);
            cnt2 = ce2 - cb2; off2 = beg2 - cb2; deg2 = end2 - beg2;
        }
        int stg[6];
        bool sv[6];
#pragma unroll
        for (int k = 0; k < 6; ++k) {
            int i = k * 64 + lane;
            sv[k] = hn && cnt2 <= 384 && i < cnt2;
            stg[k] = sv[k] ? col[cb2 + i] : 0;
        }

        // ---- aggT + GEMM for chunk c (wave-private; lgkm ordering only) ----
        *(float4*)(&aggT[wv][sg][q * 8]) = make_float4(a[0], a[1], a[2], a[3]);
        *(float4*)(&aggT[wv][sg][q * 8 + 4]) = make_float4(a[4], a[5], a[6], a[7]);

#pragma unroll
        for (int rr = 0; rr < 8; ++rr) {
            int node = c * 8 + rr;
            if (node < N) {
                float acc0 = breg, acc1 = 0.0f;
                const float4* Ar = (const float4*)(&aggT[wv][rr][0]);
#pragma unroll
                for (int k4 = 0; k4 < 16; k4 += 2) {
                    float4 av0 = Ar[k4];       // broadcast ds_read_b128, same-wave data
                    float4 av1 = Ar[k4 + 1];
                    acc0 = fmaf(av0.x, Wreg[k4 * 4 + 0], acc0);
                    acc0 = fmaf(av0.y, Wreg[k4 * 4 + 1], acc0);
                    acc0 = fmaf(av0.z, Wreg[k4 * 4 + 2], acc0);
                    acc0 = fmaf(av0.w, Wreg[k4 * 4 + 3], acc0);
                    acc1 = fmaf(av1.x, Wreg[k4 * 4 + 4], acc1);
                    acc1 = fmaf(av1.y, Wreg[k4 * 4 + 5], acc1);
                    acc1 = fmaf(av1.z, Wreg[k4 * 4 + 6], acc1);
                    acc1 = fmaf(av1.w, Wreg[k4 * 4 + 7], acc1);
                }
                float acc = acc0 + acc1;
                if (mode == 0) {
                    acc = fmaxf(acc, 0.0f) * dinv[node];
                    outh[(size_t)node * D + lane] = __float2half(acc);
                } else {
                    colacc += acc;
                    outf[(size_t)node * D + lane] = acc;
                }
            }
        }

        // ---- commit staged col values (vmcnt waits hidden under the GEMM) ----
#pragma unroll
        for (int k = 0; k < 6; ++k)
            if (sv[k]) colsh[p ^ 1][wv][k * 64 + lane] = stg[k];

        p ^= 1;
        c = c2;
        beg = beg2; deg = deg2; off = off2; cnt = cnt2;
    }

    if (mode == 1) {
        red[tid] = colacc;
        __syncthreads();
        if (wv == 0) {
            float s = red[lane] + red[64 + lane] + red[128 + lane] + red[192 + lane];
            atomicAdd(&msum[lane], s);
        }
    }
}

__global__ void finalize_kernel(const float* __restrict__ msum, float* __restrict__ outMean,
                                float invN) {
    outMean[threadIdx.x] = msum[threadIdx.x] * invN;
}

extern "C" void kernel_launch(void* const* d_in, const int* in_sizes, int n_in,
                              void* d_out, int out_size, void* d_ws, size_t ws_size,
                              hipStream_t stream) {
    const float* feat = (const float*)d_in[0];
    const int* src = (const int*)d_in[1];
    const int* dst = (const int*)d_in[2];
    const float* W0 = (const float*)d_in[3];
    const float* b0 = (const float*)d_in[4];
    const float* W1 = (const float*)d_in[5];
    const float* b1 = (const float*)d_in[6];
    const float* W2 = (const float*)d_in[7];
    const float* b2 = (const float*)d_in[8];

    const int N = in_sizes[0] / D;  // 100000
    const int E = in_sizes[1];      // 1600000
    float* out = (float*)d_out;     // [N*D + D] floats

    // workspace layout (int units), 16B-aligned blocks; NA = padded N+1
    int* wsi = (int*)d_ws;
    const size_t NA = 100352;
    int*   row_ptr  = wsi;                        // NA
    float* dinv     = (float*)(wsi + NA);         // NA
    float* msum     = (float*)(wsi + 2 * NA);     // 64 floats
    int*   tick     = wsi + 2 * NA + 64;          // 3 tickets (pad to 256)
    int*   gdst     = wsi + 2 * NA + 256;         // NBUK cursors (pad 512)
    int*   gsrc     = wsi + 2 * NA + 768;         // NBUK cursors (pad 512)
    int*   cb_dst   = wsi + 2 * NA + 1280;        // NBUK+1 (pad 512)
    int*   pairs    = wsi + 2 * NA + 1792;        // NBUK*CAP = 1,801,728
    unsigned char* skeys = (unsigned char*)(pairs + (size_t)NBUK * CAP);  // NBUK*CAP bytes
    int*   col      = pairs + (size_t)NBUK * CAP + (NBUK * CAP + 3) / 4;  // E
    __half* hsA     = (__half*)(col + (size_t)E);                         // N*D halves
    __half* hsB     = hsA + (size_t)N * D;                                // N*D halves

    hipMemsetAsync(gdst, 0, sizeof(int) * 1024, stream);   // gdst+gsrc cursors

    scatter_kernel<<<784, 256, 0, stream>>>(src, dst, gdst, gsrc, pairs, skeys, E);
    scan_kernel<<<1, 512, 0, stream>>>(gdst, cb_dst, msum, tick);
    finalize_csr_kernel<<<NBUK, 256, 0, stream>>>(pairs, skeys, gdst, gsrc, cb_dst, feat,
                                                  row_ptr, col, dinv, hsA, N);

    const int FG = 768;   // == resident capacity at 3 waves/SIMD (launch_bounds(256,3))
    fused_kernel<<<FG, 256, 0, stream>>>(hsA, row_ptr, col, W0, b0, dinv, nullptr, hsB, msum,
                                         tick + 0, N, 0);
    fused_kernel<<<FG, 256, 0, stream>>>(hsB, row_ptr, col, W1, b1, dinv, nullptr, hsA, msum,
                                         tick + 1, N, 0);
    fused_kernel<<<FG, 256, 0, stream>>>(hsA, row_ptr, col, W2, b2, dinv, out, nullptr, msum,
                                         tick + 2, N, 1);

    finalize_kernel<<<1, 64, 0, stream>>>(msum, out + (size_t)N * D, 1.0f / (float)N);
}

// Round 5
// 638.012 us; speedup vs baseline: 1.9556x; 1.9556x over previous
//
#include <hip/hip_runtime.h>
#include <hip/hip_fp16.h>

#define D 64
#define NBUK 391      // ceil(100096/256) buckets of 256 nodes (key >> 8)
#define NBIN (2 * NBUK)
#define CHUNK 8192    // edges per block in phase1/phase2 (196 blocks)
#define PBSTRIDE 256  // padded blocks-per-bin stride in transposed per_block
#define NCH 12500     // per-wave chunks: N/8

// ---- phase1: per-block coarse histograms, written bin-major (transposed) ----
__global__ __launch_bounds__(256) void phase1_kernel(const int* __restrict__ src,
                                                     const int* __restrict__ dst,
                                                     int* __restrict__ per_block, int E) {
    __shared__ int h[NBIN];
    int tid = (int)threadIdx.x;
    for (int j = tid; j < NBIN; j += 256) h[j] = 0;
    __syncthreads();
    int base = blockIdx.x * CHUNK;
    int cnt = min(CHUNK, E - base);
    for (int k = tid * 4; k < cnt; k += 1024) {
        if (k + 3 < cnt) {
            int4 d4 = *(const int4*)(dst + base + k);
            int4 s4 = *(const int4*)(src + base + k);
            atomicAdd(&h[d4.x >> 8], 1); atomicAdd(&h[d4.y >> 8], 1);
            atomicAdd(&h[d4.z >> 8], 1); atomicAdd(&h[d4.w >> 8], 1);
            atomicAdd(&h[NBUK + (s4.x >> 8)], 1); atomicAdd(&h[NBUK + (s4.y >> 8)], 1);
            atomicAdd(&h[NBUK + (s4.z >> 8)], 1); atomicAdd(&h[NBUK + (s4.w >> 8)], 1);
        } else {
            int kend = (k + 4 < cnt) ? k + 4 : cnt;
            for (int t = k; t < kend; ++t) {
                atomicAdd(&h[dst[base + t] >> 8], 1);
                atomicAdd(&h[NBUK + (src[base + t] >> 8)], 1);
            }
        }
    }
    __syncthreads();
    for (int j = tid; j < NBIN; j += 256) per_block[j * PBSTRIDE + blockIdx.x] = h[j];
}

// ---- scanA (transposed): one wave per bin scans its nblk contiguous counts ----
__global__ __launch_bounds__(256) void scanA_kernel(int* __restrict__ per_block,
                                                    int* __restrict__ total, int nblk) {
    int wv = (int)threadIdx.x >> 6;
    int lane = (int)threadIdx.x & 63;
    int j = blockIdx.x * 4 + wv;
    if (j >= NBIN) return;
    int* pb = per_block + (size_t)j * PBSTRIDE;
    int idx = lane * 4;
    int4 v = make_int4(0, 0, 0, 0);
    if (idx + 3 < nblk) {
        v = *(const int4*)(pb + idx);
    } else if (idx < nblk) {
        v.x = pb[idx];
        if (idx + 1 < nblk) v.y = pb[idx + 1];
        if (idx + 2 < nblk) v.z = pb[idx + 2];
    }
    int s1 = v.x + v.y, s2 = s1 + v.z, s3 = s2 + v.w;
    int x = s3;
#pragma unroll
    for (int d = 1; d < 64; d <<= 1) {
        int t = __shfl_up(x, d);
        if (lane >= d) x += t;
    }
    int excl = x - s3;
    int4 r = make_int4(excl, excl + v.x, excl + s1, excl + s2);
    *(int4*)(pb + idx) = r;
    if (lane == 63) total[j] = x;
}

// ---- scanB: exclusive-scan bucket totals; zero msum; init fused tickets ----
__global__ __launch_bounds__(512) void scanB_kernel(const int* __restrict__ total,
                                                    int* __restrict__ cb_dst,
                                                    int* __restrict__ cb_src,
                                                    float* __restrict__ msum,
                                                    int* __restrict__ tick) {
    __shared__ int s[512];
    int tid = (int)threadIdx.x;
    if (tid < D) msum[tid] = 0.0f;
    if (tid < 3) tick[tid] = 768 * 4;   // first 3072 chunks pre-assigned to waves
    for (int half = 0; half < 2; ++half) {
        int v = (tid < NBUK) ? total[half * NBUK + tid] : 0;
        s[tid] = v;
        __syncthreads();
        for (int off = 1; off < 512; off <<= 1) {
            int t = (tid >= off) ? s[tid - off] : 0;
            __syncthreads();
            s[tid] += t;
            __syncthreads();
        }
        int* cb = half ? cb_src : cb_dst;
        if (tid < NBUK) cb[tid] = s[tid] - v;
        if (tid == NBUK - 1) cb[NBUK] = s[tid];
        __syncthreads();
    }
}

// ---- phase2: scatter edges to bucket order via LDS cursors ----
__global__ __launch_bounds__(256) void phase2_kernel(const int* __restrict__ src,
                                                     const int* __restrict__ dst,
                                                     const int* __restrict__ per_block,
                                                     const int* __restrict__ cb_dst,
                                                     const int* __restrict__ cb_src,
                                                     int* __restrict__ pairs,
                                                     unsigned char* __restrict__ skeys, int E) {
    __shared__ int lcur[NBIN];
    int tid = (int)threadIdx.x;
    for (int j = tid; j < NBIN; j += 256)
        lcur[j] = per_block[(size_t)j * PBSTRIDE + blockIdx.x] +
                  (j < NBUK ? cb_dst[j] : cb_src[j - NBUK]);
    __syncthreads();
    int base = blockIdx.x * CHUNK;
    int cnt = min(CHUNK, E - base);
    for (int k = tid * 4; k < cnt; k += 1024) {
        if (k + 3 < cnt) {
            int4 d4 = *(const int4*)(dst + base + k);
            int4 s4 = *(const int4*)(src + base + k);
            int p;
            p = atomicAdd(&lcur[d4.x >> 8], 1); pairs[p] = (s4.x << 8) | (d4.x & 255);
            p = atomicAdd(&lcur[d4.y >> 8], 1); pairs[p] = (s4.y << 8) | (d4.y & 255);
            p = atomicAdd(&lcur[d4.z >> 8], 1); pairs[p] = (s4.z << 8) | (d4.z & 255);
            p = atomicAdd(&lcur[d4.w >> 8], 1); pairs[p] = (s4.w << 8) | (d4.w & 255);
            p = atomicAdd(&lcur[NBUK + (s4.x >> 8)], 1); skeys[p] = (unsigned char)(s4.x & 255);
            p = atomicAdd(&lcur[NBUK + (s4.y >> 8)], 1); skeys[p] = (unsigned char)(s4.y & 255);
            p = atomicAdd(&lcur[NBUK + (s4.z >> 8)], 1); skeys[p] = (unsigned char)(s4.z & 255);
            p = atomicAdd(&lcur[NBUK + (s4.w >> 8)], 1); skeys[p] = (unsigned char)(s4.w & 255);
        } else {
            int kend = (k + 4 < cnt) ? k + 4 : cnt;
            for (int t = k; t < kend; ++t) {
                int dv = dst[base + t], sv = src[base + t];
                int p = atomicAdd(&lcur[dv >> 8], 1);
                pairs[p] = (sv << 8) | (dv & 255);
                p = atomicAdd(&lcur[NBUK + (sv >> 8)], 1);
                skeys[p] = (unsigned char)(sv & 255);
            }
        }
    }
}

// ---- finalize: per bucket, dinv from src-keys; row_ptr + col from dst-pairs;
//      fused fp16 prescale of this bucket's feature rows ----
__global__ __launch_bounds__(256) void finalize_csr_kernel(const int* __restrict__ pairs,
                                                           const unsigned char* __restrict__ skeys,
                                                           const int* __restrict__ cb_dst,
                                                           const int* __restrict__ cb_src,
                                                           const float* __restrict__ feat,
                                                           int* __restrict__ row_ptr,
                                                           int* __restrict__ col,
                                                           float* __restrict__ dinv,
                                                           __half* __restrict__ hs, int N) {
    __shared__ int fine[256];
    __shared__ int lcur[256];
    __shared__ float dsh[256];
    __shared__ int wtot[4], wexcl[4];
    int b = (int)blockIdx.x;
    int tid = (int)threadIdx.x, lane = tid & 63, wv = tid >> 6;
    int g = b * 256 + tid;

    fine[tid] = 0;
    __syncthreads();
    int sb0 = cb_src[b], sb1 = cb_src[b + 1];
    for (int i = sb0 + tid; i < sb1; i += 256) atomicAdd(&fine[skeys[i]], 1);
    __syncthreads();
    float dv_ = 1.0f / fmaxf((float)fine[tid], 1.0f);
    dsh[tid] = dv_;
    if (g < N) dinv[g] = dv_;
    __syncthreads();

    {
        int q = tid & 7;
        int rbase = tid >> 3;
        for (int p = 0; p < 8; ++p) {
            int r = p * 32 + rbase;
            int node = b * 256 + r;
            if (node < N) {
                float sc = dsh[r];
                const float4* f = (const float4*)(feat + (size_t)node * D + q * 8);
                float4 v0 = f[0], v1 = f[1];
                __half2 h[4];
                h[0] = __floats2half2_rn(v0.x * sc, v0.y * sc);
                h[1] = __floats2half2_rn(v0.z * sc, v0.w * sc);
                h[2] = __floats2half2_rn(v1.x * sc, v1.y * sc);
                h[3] = __floats2half2_rn(v1.z * sc, v1.w * sc);
                *(float4*)(hs + (size_t)node * D + q * 8) = *(float4*)h;
            }
        }
    }
    __syncthreads();

    fine[tid] = 0;
    __syncthreads();
    int cb0 = cb_dst[b], cb1 = cb_dst[b + 1];
    for (int i = cb0 + tid; i < cb1; i += 256) atomicAdd(&fine[pairs[i] & 255], 1);
    __syncthreads();
    int v = fine[tid], x = v;
#pragma unroll
    for (int d = 1; d < 64; d <<= 1) {
        int t = __shfl_up(x, d);
        if (lane >= d) x += t;
    }
    if (lane == 63) wtot[wv] = x;
    __syncthreads();
    if (tid == 0) {
        int a = 0;
#pragma unroll
        for (int k = 0; k < 4; ++k) { wexcl[k] = a; a += wtot[k]; }
    }
    __syncthreads();
    int excl = x - v + wexcl[wv];
    if (g <= N) row_ptr[g] = cb0 + excl;
    lcur[tid] = cb0 + excl;
    __syncthreads();
    for (int i = cb0 + tid; i < cb1; i += 256) {
        int p = pairs[i];
        int pos = atomicAdd(&lcur[p & 255], 1);
        col[pos] = p >> 8;
    }
}

__device__ inline void accum8(float* a, float4 raw) {
    __half2* h = (__half2*)&raw;
#pragma unroll
    for (int k = 0; k < 4; ++k) {
        float2 f = __half22float2(h[k]);
        a[2 * k] += f.x;
        a[2 * k + 1] += f.y;
    }
}

// ---- fused gather(fp16) + GEMM (+ column-sum on final layer) ----
// R16 == R15 resubmitted verbatim (R15 bench was an infra failure: container
// died twice, no counters; this source is R3's verified fused kernel +
// R1/R2's verified preprocessing).
// Gather: three structurally different pipelines (R0/R1/R2) converged at
// 67+-5us => per-CU miss-concurrency cap (~17 lines in flight at ~430cy avg
// latency, Little's law). Don't re-plumb.
// Tickets: waves own 8-row chunks; next chunk fetched via atomicAdd issued
// at gather-start (latency hidden under gather); ~12.5k atomics/layer on one
// line = one per ~5ns, no contention. Removes the 3125/768=4.07-round tail.
// HARD RULE: grid == resident capacity = 768 @ launch_bounds(256,3).
__global__ __launch_bounds__(256, 3) void fused_kernel(const __half* __restrict__ hs_in,
                                                       const int* __restrict__ row_ptr,
                                                       const int* __restrict__ col,
                                                       const float* __restrict__ W,
                                                       const float* __restrict__ bias,
                                                       const float* __restrict__ dinv,
                                                       float* __restrict__ outf,
                                                       __half* __restrict__ outh,
                                                       float* __restrict__ msum,
                                                       int* __restrict__ tick,
                                                       int N, int mode) {
    __shared__ int colsh[2][4][384];    // [buf][wave][slot]
    __shared__ float aggT[4][8][68];    // [wave][row][d]
    __shared__ float red[256];
    int tid = (int)threadIdx.x;
    int lane = tid & 63;
    int wv = tid >> 6;
    int sg = lane >> 3;       // row-slot 0..7 within wave
    int q = lane & 7;         // 8 lanes per row, 16B (8 halves) each

    float Wreg[64];
#pragma unroll
    for (int k = 0; k < 64; ++k) Wreg[k] = W[k * 64 + lane];
    float breg = bias[lane];
    float colacc = 0.0f;

    int c = (int)blockIdx.x * 4 + wv;   // initial chunk: pre-assigned

    int beg, deg, off, cnt;
    {
        int node = c * 8 + sg;
        beg = row_ptr[min(node, N)];
        int end = row_ptr[min(node + 1, N)];
        int cb = __shfl(beg, 0);        // lane 0: sg=0,q=0 -> row_ptr[c*8]
        int ce = __shfl(end, 56);       // lane 56: sg=7 -> row_ptr[c*8+8]
        cnt = ce - cb; off = beg - cb; deg = end - beg;
        if (cnt <= 384) {
#pragma unroll
            for (int k = 0; k < 6; ++k) {
                int i = k * 64 + lane;
                if (i < cnt) colsh[0][wv][i] = col[cb + i];
            }
        }
    }
    int p = 0;

    while (c < NCH) {
        int tkt = 0;
        if (lane == 0) tkt = atomicAdd(tick, 1);   // issue early; consumed post-gather

        int md = deg;                  // wave-max degree (groups on lane bits 3..5)
        md = max(md, __shfl_xor(md, 8));
        md = max(md, __shfl_xor(md, 16));
        md = max(md, __shfl_xor(md, 32));
        int rounds = (md + 3) >> 2;

        float a[8];
#pragma unroll
        for (int k = 0; k < 8; ++k) a[k] = 0.0f;

        if (cnt <= 384) {
            const int* cbuf = &colsh[p][wv][0];
            int cl = cnt - 1;          // clamp: overflow lanes dup a valid col -> L1-hit
            float4 A0, A1, A2, A3, B0, B1, B2, B3;
#define LD1(dstv, e_) { int ci = min(off + (e_), cl); int srcn = cbuf[ci]; \
                        dstv = *(const float4*)(hs_in + (size_t)srcn * D + q * 8); }
#define ISS(X0, X1, X2, X3, b_) { int eb = (b_) << 2; \
        LD1(X0, eb) LD1(X1, eb + 1) LD1(X2, eb + 2) LD1(X3, eb + 3) }
#define CNS(X0, X1, X2, X3, b_) { int eb = (b_) << 2; \
        if (eb < deg) accum8(a, X0); if (eb + 1 < deg) accum8(a, X1); \
        if (eb + 2 < deg) accum8(a, X2); if (eb + 3 < deg) accum8(a, X3); }
            if (rounds > 0) {
                ISS(A0, A1, A2, A3, 0)
                if (rounds > 1) ISS(B0, B1, B2, B3, 1)
                int b = 0;
                while (true) {
                    CNS(A0, A1, A2, A3, b)
                    if (b + 2 < rounds) ISS(A0, A1, A2, A3, b + 2)
                    ++b; if (b >= rounds) break;
                    CNS(B0, B1, B2, B3, b)
                    if (b + 2 < rounds) ISS(B0, B1, B2, B3, b + 2)
                    ++b; if (b >= rounds) break;
                }
            }
#undef LD1
#undef ISS
#undef CNS
        } else {
            int end = beg + deg;
            for (int j = beg; j < end; ++j) {
                int s0 = col[j];
                float4 r0 = *(const float4*)(hs_in + (size_t)s0 * D + q * 8);
                accum8(a, r0);
            }
        }

        // ---- next chunk via ticket; stage meta + col values into REGS ----
        int c2 = __shfl(tkt, 0);
        bool hn = c2 < NCH;
        int beg2 = 0, deg2 = 0, off2 = 0, cnt2 = 0, cb2 = 0;
        if (hn) {
            int node2 = c2 * 8 + sg;
            beg2 = row_ptr[min(node2, N)];
            int end2 = row_ptr[min(node2 + 1, N)];
            cb2 = __shfl(beg2, 0);
            int ce2 = __shfl(end2, 56);
            cnt2 = ce2 - cb2; off2 = beg2 - cb2; deg2 = end2 - beg2;
        }
        int stg[6];
        bool sv[6];
#pragma unroll
        for (int k = 0; k < 6; ++k) {
            int i = k * 64 + lane;
            sv[k] = hn && cnt2 <= 384 && i < cnt2;
            stg[k] = sv[k] ? col[cb2 + i] : 0;
        }

        // ---- aggT + GEMM for chunk c (wave-private; lgkm ordering only) ----
        *(float4*)(&aggT[wv][sg][q * 8]) = make_float4(a[0], a[1], a[2], a[3]);
        *(float4*)(&aggT[wv][sg][q * 8 + 4]) = make_float4(a[4], a[5], a[6], a[7]);

#pragma unroll
        for (int rr = 0; rr < 8; ++rr) {
            int node = c * 8 + rr;
            if (node < N) {
                float acc0 = breg, acc1 = 0.0f;
                const float4* Ar = (const float4*)(&aggT[wv][rr][0]);
#pragma unroll
                for (int k4 = 0; k4 < 16; k4 += 2) {
                    float4 av0 = Ar[k4];       // broadcast ds_read_b128, same-wave data
                    float4 av1 = Ar[k4 + 1];
                    acc0 = fmaf(av0.x, Wreg[k4 * 4 + 0], acc0);
                    acc0 = fmaf(av0.y, Wreg[k4 * 4 + 1], acc0);
                    acc0 = fmaf(av0.z, Wreg[k4 * 4 + 2], acc0);
                    acc0 = fmaf(av0.w, Wreg[k4 * 4 + 3], acc0);
                    acc1 = fmaf(av1.x, Wreg[k4 * 4 + 4], acc1);
                    acc1 = fmaf(av1.y, Wreg[k4 * 4 + 5], acc1);
                    acc1 = fmaf(av1.z, Wreg[k4 * 4 + 6], acc1);
                    acc1 = fmaf(av1.w, Wreg[k4 * 4 + 7], acc1);
                }
                float acc = acc0 + acc1;
                if (mode == 0) {
                    acc = fmaxf(acc, 0.0f) * dinv[node];
                    outh[(size_t)node * D + lane] = __float2half(acc);
                } else {
                    colacc += acc;
                    outf[(size_t)node * D + lane] = acc;
                }
            }
        }

        // ---- commit staged col values (vmcnt waits hidden under the GEMM) ----
#pragma unroll
        for (int k = 0; k < 6; ++k)
            if (sv[k]) colsh[p ^ 1][wv][k * 64 + lane] = stg[k];

        p ^= 1;
        c = c2;
        beg = beg2; deg = deg2; off = off2; cnt = cnt2;
    }

    if (mode == 1) {
        red[tid] = colacc;
        __syncthreads();
        if (wv == 0) {
            float s = red[lane] + red[64 + lane] + red[128 + lane] + red[192 + lane];
            atomicAdd(&msum[lane], s);
        }
    }
}

__global__ void finalize_kernel(const float* __restrict__ msum, float* __restrict__ outMean,
                                float invN) {
    outMean[threadIdx.x] = msum[threadIdx.x] * invN;
}

extern "C" void kernel_launch(void* const* d_in, const int* in_sizes, int n_in,
                              void* d_out, int out_size, void* d_ws, size_t ws_size,
                              hipStream_t stream) {
    const float* feat = (const float*)d_in[0];
    const int* src = (const int*)d_in[1];
    const int* dst = (const int*)d_in[2];
    const float* W0 = (const float*)d_in[3];
    const float* b0 = (const float*)d_in[4];
    const float* W1 = (const float*)d_in[5];
    const float* b1 = (const float*)d_in[6];
    const float* W2 = (const float*)d_in[7];
    const float* b2 = (const float*)d_in[8];

    const int N = in_sizes[0] / D;  // 100000
    const int E = in_sizes[1];      // 1600000
    float* out = (float*)d_out;     // [N*D + D] floats

    const int NBLK = (E + CHUNK - 1) / CHUNK;  // 196 <= PBSTRIDE

    // workspace layout (int units), 16B-aligned offsets; NA = padded N+1
    int* wsi = (int*)d_ws;
    const size_t NA = 100352;
    int*   row_ptr  = wsi;                       // NA
    float* dinv     = (float*)(wsi + NA);        // NA
    float* msum     = (float*)(wsi + 2 * NA);    // 64 floats
    int*   tick     = wsi + 2 * NA + 64;         // 3 tickets (within msum's 256 pad)
    int*   total    = wsi + 2 * NA + 256;        // 782 (pad 1024)
    int*   cb_dst   = wsi + 2 * NA + 1280;       // 392 (pad 512)
    int*   cb_src   = wsi + 2 * NA + 1792;       // 392 (pad 512)
    int*   per_blk  = wsi + 2 * NA + 2304;       // NBIN*PBSTRIDE = 200192 (pad 200704)
    int*   pairs    = wsi + 2 * NA + 203008;     // E
    unsigned char* skeys = (unsigned char*)(pairs + (size_t)E);  // E bytes (pad -> 400000 ints)
    int*   col      = pairs + (size_t)E + 400000;                // E
    __half* hsA     = (__half*)(col + (size_t)E);                // N*D halves
    __half* hsB     = hsA + (size_t)N * D;                       // N*D halves

    phase1_kernel<<<NBLK, 256, 0, stream>>>(src, dst, per_blk, E);
    scanA_kernel<<<(NBIN + 3) / 4, 256, 0, stream>>>(per_blk, total, NBLK);
    scanB_kernel<<<1, 512, 0, stream>>>(total, cb_dst, cb_src, msum, tick);
    phase2_kernel<<<NBLK, 256, 0, stream>>>(src, dst, per_blk, cb_dst, cb_src, pairs, skeys, E);
    finalize_csr_kernel<<<NBUK, 256, 0, stream>>>(pairs, skeys, cb_dst, cb_src, feat,
                                                  row_ptr, col, dinv, hsA, N);

    const int FG = 768;   // == resident capacity at 3 waves/SIMD (launch_bounds(256,3))
    fused_kernel<<<FG, 256, 0, stream>>>(hsA, row_ptr, col, W0, b0, dinv, nullptr, hsB, msum,
                                         tick + 0, N, 0);
    fused_kernel<<<FG, 256, 0, stream>>>(hsB, row_ptr, col, W1, b1, dinv, nullptr, hsA, msum,
                                         tick + 1, N, 0);
    fused_kernel<<<FG, 256, 0, stream>>>(hsA, row_ptr, col, W2, b2, dinv, out, nullptr, msum,
                                         tick + 2, N, 1);

    finalize_kernel<<<1, 64, 0, stream>>>(msum, out + (size_t)N * D, 1.0f / (float)N);
}

// Round 6
// 363.306 us; speedup vs baseline: 3.4343x; 1.7561x over previous
//
#include <hip/hip_runtime.h>
#include <hip/hip_fp16.h>

#define D 64
#define NBUK 391      // ceil(100096/256) buckets of 256 nodes (key >> 8)
#define CHUNK 8192    // edges per block in phase1/phase2 (196 blocks)
#define PBSTRIDE 256  // padded blocks-per-bin stride in transposed per_block

// ---- phase1: per-block dst histograms (transposed) + global out-degree ----
// src-half of the sort is GONE (R6): out-degree computed directly via global
// atomics -- 1.6M adds over 100k addresses = 16/address (R3's 645us disaster
// was 4090/address; 16/address prices at ~2-3us total).
__global__ __launch_bounds__(256) void phase1_kernel(const int* __restrict__ src,
                                                     const int* __restrict__ dst,
                                                     int* __restrict__ per_block,
                                                     int* __restrict__ degg, int E) {
    __shared__ int h[NBUK];
    int tid = (int)threadIdx.x;
    for (int j = tid; j < NBUK; j += 256) h[j] = 0;
    __syncthreads();
    int base = blockIdx.x * CHUNK;
    int cnt = min(CHUNK, E - base);
    for (int k = tid * 4; k < cnt; k += 1024) {
        if (k + 3 < cnt) {
            int4 d4 = *(const int4*)(dst + base + k);
            int4 s4 = *(const int4*)(src + base + k);
            atomicAdd(&h[d4.x >> 8], 1); atomicAdd(&h[d4.y >> 8], 1);
            atomicAdd(&h[d4.z >> 8], 1); atomicAdd(&h[d4.w >> 8], 1);
            atomicAdd(&degg[s4.x], 1); atomicAdd(&degg[s4.y], 1);
            atomicAdd(&degg[s4.z], 1); atomicAdd(&degg[s4.w], 1);
        } else {
            int kend = (k + 4 < cnt) ? k + 4 : cnt;
            for (int t = k; t < kend; ++t) {
                atomicAdd(&h[dst[base + t] >> 8], 1);
                atomicAdd(&degg[src[base + t]], 1);
            }
        }
    }
    __syncthreads();
    for (int j = tid; j < NBUK; j += 256) per_block[j * PBSTRIDE + blockIdx.x] = h[j];
}

// ---- scanA (transposed): one wave per bin scans its nblk contiguous counts ----
__global__ __launch_bounds__(256) void scanA_kernel(int* __restrict__ per_block,
                                                    int* __restrict__ total, int nblk) {
    int wv = (int)threadIdx.x >> 6;
    int lane = (int)threadIdx.x & 63;
    int j = blockIdx.x * 4 + wv;
    if (j >= NBUK) return;
    int* pb = per_block + (size_t)j * PBSTRIDE;
    int idx = lane * 4;
    int4 v = make_int4(0, 0, 0, 0);
    if (idx + 3 < nblk) {
        v = *(const int4*)(pb + idx);
    } else if (idx < nblk) {
        v.x = pb[idx];
        if (idx + 1 < nblk) v.y = pb[idx + 1];
        if (idx + 2 < nblk) v.z = pb[idx + 2];
    }
    int s1 = v.x + v.y, s2 = s1 + v.z, s3 = s2 + v.w;
    int x = s3;
#pragma unroll
    for (int d = 1; d < 64; d <<= 1) {
        int t = __shfl_up(x, d);
        if (lane >= d) x += t;
    }
    int excl = x - s3;
    int4 r = make_int4(excl, excl + v.x, excl + s1, excl + s2);
    *(int4*)(pb + idx) = r;
    if (lane == 63) total[j] = x;
}

// ---- scanB: exclusive-scan dst bucket totals; zero msum ----
__global__ __launch_bounds__(512) void scanB_kernel(const int* __restrict__ total,
                                                    int* __restrict__ cb_dst,
                                                    float* __restrict__ msum) {
    __shared__ int s[512];
    int tid = (int)threadIdx.x;
    if (tid < D) msum[tid] = 0.0f;
    int v = (tid < NBUK) ? total[tid] : 0;
    s[tid] = v;
    __syncthreads();
    for (int off = 1; off < 512; off <<= 1) {
        int t = (tid >= off) ? s[tid - off] : 0;
        __syncthreads();
        s[tid] += t;
        __syncthreads();
    }
    if (tid < NBUK) cb_dst[tid] = s[tid] - v;
    if (tid == NBUK - 1) cb_dst[NBUK] = s[tid];
}

// ---- phase2: scatter edges to dst-bucket order via LDS cursors ----
__global__ __launch_bounds__(256) void phase2_kernel(const int* __restrict__ src,
                                                     const int* __restrict__ dst,
                                                     const int* __restrict__ per_block,
                                                     const int* __restrict__ cb_dst,
                                                     int* __restrict__ pairs, int E) {
    __shared__ int lcur[NBUK];
    int tid = (int)threadIdx.x;
    for (int j = tid; j < NBUK; j += 256)
        lcur[j] = per_block[(size_t)j * PBSTRIDE + blockIdx.x] + cb_dst[j];
    __syncthreads();
    int base = blockIdx.x * CHUNK;
    int cnt = min(CHUNK, E - base);
    for (int k = tid * 4; k < cnt; k += 1024) {
        if (k + 3 < cnt) {
            int4 d4 = *(const int4*)(dst + base + k);
            int4 s4 = *(const int4*)(src + base + k);
            int p;
            p = atomicAdd(&lcur[d4.x >> 8], 1); pairs[p] = (s4.x << 8) | (d4.x & 255);
            p = atomicAdd(&lcur[d4.y >> 8], 1); pairs[p] = (s4.y << 8) | (d4.y & 255);
            p = atomicAdd(&lcur[d4.z >> 8], 1); pairs[p] = (s4.z << 8) | (d4.z & 255);
            p = atomicAdd(&lcur[d4.w >> 8], 1); pairs[p] = (s4.w << 8) | (d4.w & 255);
        } else {
            int kend = (k + 4 < cnt) ? k + 4 : cnt;
            for (int t = k; t < kend; ++t) {
                int dv = dst[base + t], sv = src[base + t];
                int p = atomicAdd(&lcur[dv >> 8], 1);
                pairs[p] = (sv << 8) | (dv & 255);
            }
        }
    }
}

// ---- finalize: dinv from degg; row_ptr + col from dst-pairs;
//      fused fp16 prescale of this bucket's feature rows ----
__global__ __launch_bounds__(256) void finalize_csr_kernel(const int* __restrict__ pairs,
                                                           const int* __restrict__ degg,
                                                           const int* __restrict__ cb_dst,
                                                           const float* __restrict__ feat,
                                                           int* __restrict__ row_ptr,
                                                           int* __restrict__ col,
                                                           float* __restrict__ dinv,
                                                           __half* __restrict__ hs, int N) {
    __shared__ int fine[256];
    __shared__ int lcur[256];
    __shared__ float dsh[256];
    __shared__ int wtot[4], wexcl[4];
    int b = (int)blockIdx.x;
    int tid = (int)threadIdx.x, lane = tid & 63, wv = tid >> 6;
    int g = b * 256 + tid;

    // out-degree -> dinv (direct coalesced read; src fine-hist eliminated)
    int dg = (g < N) ? degg[g] : 0;
    float dv_ = 1.0f / fmaxf((float)dg, 1.0f);
    dsh[tid] = dv_;
    if (g < N) dinv[g] = dv_;
    __syncthreads();

    // prescale this bucket's rows: hs[node][:] = half(feat[node][:] * dinv[node])
    {
        int q = tid & 7;
        int rbase = tid >> 3;
        for (int p = 0; p < 8; ++p) {
            int r = p * 32 + rbase;
            int node = b * 256 + r;
            if (node < N) {
                float sc = dsh[r];
                const float4* f = (const float4*)(feat + (size_t)node * D + q * 8);
                float4 v0 = f[0], v1 = f[1];
                __half2 h[4];
                h[0] = __floats2half2_rn(v0.x * sc, v0.y * sc);
                h[1] = __floats2half2_rn(v0.z * sc, v0.w * sc);
                h[2] = __floats2half2_rn(v1.x * sc, v1.y * sc);
                h[3] = __floats2half2_rn(v1.z * sc, v1.w * sc);
                *(float4*)(hs + (size_t)node * D + q * 8) = *(float4*)h;
            }
        }
    }

    // in-degree fine hist (dst half)
    fine[tid] = 0;
    __syncthreads();
    int cb0 = cb_dst[b], cb1 = cb_dst[b + 1];
    for (int i = cb0 + tid; i < cb1; i += 256) atomicAdd(&fine[pairs[i] & 255], 1);
    __syncthreads();
    int v = fine[tid], x = v;
#pragma unroll
    for (int d = 1; d < 64; d <<= 1) {
        int t = __shfl_up(x, d);
        if (lane >= d) x += t;
    }
    if (lane == 63) wtot[wv] = x;
    __syncthreads();
    if (tid == 0) {
        int a = 0;
#pragma unroll
        for (int k = 0; k < 4; ++k) { wexcl[k] = a; a += wtot[k]; }
    }
    __syncthreads();
    int excl = x - v + wexcl[wv];
    if (g <= N) row_ptr[g] = cb0 + excl;
    lcur[tid] = cb0 + excl;
    __syncthreads();
    for (int i = cb0 + tid; i < cb1; i += 256) {
        int p = pairs[i];
        int pos = atomicAdd(&lcur[p & 255], 1);
        col[pos] = p >> 8;
    }
}

__device__ inline void accum8(float* a, float4 raw) {
    __half2* h = (__half2*)&raw;
#pragma unroll
    for (int k = 0; k < 4; ++k) {
        float2 f = __half22float2(h[k]);
        a[2 * k] += f.x;
        a[2 * k + 1] += f.y;
    }
}

// ---- fused gather(fp16) + GEMM (+ column-sum on final layer) ----
// R6 of this session: REVERTED to the R2 structure verbatim (best measured:
// 66.7us/layer). R5 post-mortem: per-wave tickets paced the whole kernel on
// one cache line's atomic RMW queue (12.5k same-address returning atomics =
// 75M/s service rate => 168us/layer, VALUBusy 31->13%). Static block-strided
// tiles restored; the ~3-4us/layer tail imbalance is accepted as cheaper
// than any global-atomic cure (twice-measured: R3 645us, R5 168us).
// Gather: three structurally different pipelines (R0/R1/R2) converged at
// 67+-5us => per-CU miss-concurrency cap (~17-27 lines in flight at ~430cy
// avg latency, Little's law). Don't re-plumb.
// HARD RULE: grid == resident capacity = 768 @ launch_bounds(256,3).
__global__ __launch_bounds__(256, 3) void fused_kernel(const __half* __restrict__ hs_in,
                                                       const int* __restrict__ row_ptr,
                                                       const int* __restrict__ col,
                                                       const float* __restrict__ W,
                                                       const float* __restrict__ bias,
                                                       const float* __restrict__ dinv,
                                                       float* __restrict__ outf,
                                                       __half* __restrict__ outh,
                                                       float* __restrict__ msum,
                                                       int N, int mode) {
    __shared__ int colsh[2][4][384];    // [buf][wave][slot]
    __shared__ float aggT[4][8][68];    // [wave][row][d]
    __shared__ float red[256];
    int tid = (int)threadIdx.x;
    int lane = tid & 63;
    int wv = tid >> 6;
    int sg = lane >> 3;       // row-slot 0..7 within wave
    int q = lane & 7;         // 8 lanes per row, 16B (8 halves) each
    int g = wv * 8 + sg;      // block row 0..31

    float Wreg[64];
#pragma unroll
    for (int k = 0; k < 64; ++k) Wreg[k] = W[k * 64 + lane];
    float breg = bias[lane];
    float colacc = 0.0f;

    int ntiles = (N + 31) >> 5;
    int tile = (int)blockIdx.x;

    int beg, deg, off, cnt;
    {
        int node = tile * 32 + g;
        beg = row_ptr[min(node, N)];
        int end = row_ptr[min(node + 1, N)];
        int cb = __shfl(beg, 0);        // lane 0: sg=0,q=0 -> row_ptr[wfirst]
        int ce = __shfl(end, 56);       // lane 56: sg=7 -> row_ptr[wfirst+8]
        cnt = ce - cb; off = beg - cb; deg = end - beg;
        if (cnt <= 384) {
#pragma unroll
            for (int k = 0; k < 6; ++k) {
                int i = k * 64 + lane;
                if (i < cnt) colsh[0][wv][i] = col[cb + i];
            }
        }
    }
    int p = 0;

    while (tile < ntiles) {
        int md = deg;                  // wave-max degree (groups on lane bits 3..5)
        md = max(md, __shfl_xor(md, 8));
        md = max(md, __shfl_xor(md, 16));
        md = max(md, __shfl_xor(md, 32));
        int rounds = (md + 3) >> 2;

        float a[8];
#pragma unroll
        for (int k = 0; k < 8; ++k) a[k] = 0.0f;

        if (cnt <= 384) {
            const int* cbuf = &colsh[p][wv][0];
            int cl = cnt - 1;          // clamp: overflow lanes dup a valid col -> L1-hit
            float4 A0, A1, A2, A3, B0, B1, B2, B3;
#define LD1(dstv, e_) { int ci = min(off + (e_), cl); int srcn = cbuf[ci]; \
                        dstv = *(const float4*)(hs_in + (size_t)srcn * D + q * 8); }
#define ISS(X0, X1, X2, X3, b_) { int eb = (b_) << 2; \
        LD1(X0, eb) LD1(X1, eb + 1) LD1(X2, eb + 2) LD1(X3, eb + 3) }
#define CNS(X0, X1, X2, X3, b_) { int eb = (b_) << 2; \
        if (eb < deg) accum8(a, X0); if (eb + 1 < deg) accum8(a, X1); \
        if (eb + 2 < deg) accum8(a, X2); if (eb + 3 < deg) accum8(a, X3); }
            if (rounds > 0) {
                ISS(A0, A1, A2, A3, 0)
                if (rounds > 1) ISS(B0, B1, B2, B3, 1)
                int b = 0;
                while (true) {
                    CNS(A0, A1, A2, A3, b)
                    if (b + 2 < rounds) ISS(A0, A1, A2, A3, b + 2)
                    ++b; if (b >= rounds) break;
                    CNS(B0, B1, B2, B3, b)
                    if (b + 2 < rounds) ISS(B0, B1, B2, B3, b + 2)
                    ++b; if (b >= rounds) break;
                }
            }
#undef LD1
#undef ISS
#undef CNS
        } else {
            int end = beg + deg;
            for (int j = beg; j < end; ++j) {
                int s0 = col[j];
                float4 r0 = *(const float4*)(hs_in + (size_t)s0 * D + q * 8);
                accum8(a, r0);
            }
        }

        // ---- prefetch next tile: meta + col values into REGS (loads issue
        //      here, dependent ds_writes land AFTER the GEMM) ----
        int tile2 = tile + (int)gridDim.x;
        bool hn = tile2 < ntiles;
        int beg2 = 0, deg2 = 0, off2 = 0, cnt2 = 0, cb2 = 0;
        if (hn) {
            int node2 = tile2 * 32 + g;
            beg2 = row_ptr[min(node2, N)];
            int end2 = row_ptr[min(node2 + 1, N)];
            cb2 = __shfl(beg2, 0);
            int ce2 = __shfl(end2, 56);
            cnt2 = ce2 - cb2; off2 = beg2 - cb2; deg2 = end2 - beg2;
        }
        int stg[6];
        bool sv[6];
#pragma unroll
        for (int k = 0; k < 6; ++k) {
            int i = k * 64 + lane;
            sv[k] = hn && cnt2 <= 384 && i < cnt2;
            stg[k] = sv[k] ? col[cb2 + i] : 0;
        }

        // ---- aggT + GEMM (wave-private rows; lgkm ordering only) ----
        *(float4*)(&aggT[wv][sg][q * 8]) = make_float4(a[0], a[1], a[2], a[3]);
        *(float4*)(&aggT[wv][sg][q * 8 + 4]) = make_float4(a[4], a[5], a[6], a[7]);

#pragma unroll
        for (int rr = 0; rr < 8; ++rr) {
            int node = tile * 32 + wv * 8 + rr;
            if (node < N) {
                float acc0 = breg, acc1 = 0.0f;
                const float4* Ar = (const float4*)(&aggT[wv][rr][0]);
#pragma unroll
                for (int k4 = 0; k4 < 16; k4 += 2) {
                    float4 av0 = Ar[k4];       // broadcast ds_read_b128, same-wave data
                    float4 av1 = Ar[k4 + 1];
                    acc0 = fmaf(av0.x, Wreg[k4 * 4 + 0], acc0);
                    acc0 = fmaf(av0.y, Wreg[k4 * 4 + 1], acc0);
                    acc0 = fmaf(av0.z, Wreg[k4 * 4 + 2], acc0);
                    acc0 = fmaf(av0.w, Wreg[k4 * 4 + 3], acc0);
                    acc1 = fmaf(av1.x, Wreg[k4 * 4 + 4], acc1);
                    acc1 = fmaf(av1.y, Wreg[k4 * 4 + 5], acc1);
                    acc1 = fmaf(av1.z, Wreg[k4 * 4 + 6], acc1);
                    acc1 = fmaf(av1.w, Wreg[k4 * 4 + 7], acc1);
                }
                float acc = acc0 + acc1;
                if (mode == 0) {
                    acc = fmaxf(acc, 0.0f) * dinv[node];
                    outh[(size_t)node * D + lane] = __float2half(acc);
                } else {
                    colacc += acc;
                    outf[(size_t)node * D + lane] = acc;
                }
            }
        }

        // ---- commit staged col values (vmcnt waits hidden under the GEMM) ----
#pragma unroll
        for (int k = 0; k < 6; ++k)
            if (sv[k]) colsh[p ^ 1][wv][k * 64 + lane] = stg[k];

        p ^= 1;
        tile = tile2;
        beg = beg2; deg = deg2; off = off2; cnt = cnt2;
    }

    if (mode == 1) {
        red[tid] = colacc;
        __syncthreads();
        if (wv == 0) {
            float s = red[lane] + red[64 + lane] + red[128 + lane] + red[192 + lane];
            atomicAdd(&msum[lane], s);
        }
    }
}

__global__ void finalize_kernel(const float* __restrict__ msum, float* __restrict__ outMean,
                                float invN) {
    outMean[threadIdx.x] = msum[threadIdx.x] * invN;
}

extern "C" void kernel_launch(void* const* d_in, const int* in_sizes, int n_in,
                              void* d_out, int out_size, void* d_ws, size_t ws_size,
                              hipStream_t stream) {
    const float* feat = (const float*)d_in[0];
    const int* src = (const int*)d_in[1];
    const int* dst = (const int*)d_in[2];
    const float* W0 = (const float*)d_in[3];
    const float* b0 = (const float*)d_in[4];
    const float* W1 = (const float*)d_in[5];
    const float* b1 = (const float*)d_in[6];
    const float* W2 = (const float*)d_in[7];
    const float* b2 = (const float*)d_in[8];

    const int N = in_sizes[0] / D;  // 100000
    const int E = in_sizes[1];      // 1600000
    float* out = (float*)d_out;     // [N*D + D] floats

    const int NBLK = (E + CHUNK - 1) / CHUNK;  // 196 <= PBSTRIDE

    // workspace layout (int units), 16B-aligned offsets; NA = padded N+1
    int* wsi = (int*)d_ws;
    const size_t NA = 100352;
    int*   row_ptr  = wsi;                       // NA
    float* dinv     = (float*)(wsi + NA);        // NA
    float* msum     = (float*)(wsi + 2 * NA);    // 64 (pad 256)
    int*   total    = wsi + 2 * NA + 256;        // 391 (pad 512)
    int*   cb_dst   = wsi + 2 * NA + 768;        // 392 (pad 512)
    int*   degg     = wsi + 2 * NA + 1280;       // NA out-degree counters
    int*   per_blk  = wsi + 2 * NA + 1280 + NA;  // NBUK*PBSTRIDE = 100096 (pad 100352)
    int*   pairs    = wsi + 2 * NA + 1280 + NA + 100352;   // E
    int*   col      = pairs + (size_t)E;                   // E
    __half* hsA     = (__half*)(col + (size_t)E);          // N*D halves
    __half* hsB     = hsA + (size_t)N * D;                 // N*D halves

    hipMemsetAsync(degg, 0, sizeof(int) * (size_t)N, stream);

    phase1_kernel<<<NBLK, 256, 0, stream>>>(src, dst, per_blk, degg, E);
    scanA_kernel<<<(NBUK + 3) / 4, 256, 0, stream>>>(per_blk, total, NBLK);
    scanB_kernel<<<1, 512, 0, stream>>>(total, cb_dst, msum);
    phase2_kernel<<<NBLK, 256, 0, stream>>>(src, dst, per_blk, cb_dst, pairs, E);
    finalize_csr_kernel<<<NBUK, 256, 0, stream>>>(pairs, degg, cb_dst, feat,
                                                  row_ptr, col, dinv, hsA, N);

    const int FG = 768;   // == resident capacity at 3 waves/SIMD (launch_bounds(256,3))
    fused_kernel<<<FG, 256, 0, stream>>>(hsA, row_ptr, col, W0, b0, dinv, nullptr, hsB, msum, N, 0);
    fused_kernel<<<FG, 256, 0, stream>>>(hsB, row_ptr, col, W1, b1, dinv, nullptr, hsA, msum, N, 0);
    fused_kernel<<<FG, 256, 0, stream>>>(hsA, row_ptr, col, W2, b2, dinv, out, nullptr, msum, N, 1);

    finalize_kernel<<<1, 64, 0, stream>>>(msum, out + (size_t)N * D, 1.0f / (float)N);
}

// Round 8
// 319.690 us; speedup vs baseline: 3.9028x; 1.1364x over previous
//
#include <hip/hip_runtime.h>
#include <hip/hip_fp16.h>

#define D 64
#define NBUK 391      // ceil(100096/256) buckets of 256 nodes (key >> 8)
#define NBIN (2 * NBUK)
#define CHUNK 6272    // edges per block in phase1/phase2 -> 256 blocks (1/CU)
#define PBSTRIDE 256  // padded blocks-per-bin stride; NBLK must stay <= 256

// ======== PREPROCESSING: R1-proven dual-bucket LDS-cursor sort (FROZEN) ========
// Atomic ledger (do not revisit): global cursors 4090/addr = 645us (R3);
// 1-addr blocking ticket = +100us/layer (R5); 16/addr fire-and-forget = +45us
// (R6 degg). LDS cursors + transposed per-block scan is the proven structure.
// R7 lesson: cg::grid.sync() does NOT give cross-XCD L2 coherence for the
// layer ping-pong (absmax 7.8e-2) -- kernel boundaries are the fence. FROZEN.

__global__ __launch_bounds__(256) void phase1_kernel(const int* __restrict__ src,
                                                     const int* __restrict__ dst,
                                                     int* __restrict__ per_block, int E) {
    __shared__ int h[NBIN];
    int tid = (int)threadIdx.x;
    for (int j = tid; j < NBIN; j += 256) h[j] = 0;
    __syncthreads();
    int base = blockIdx.x * CHUNK;
    int cnt = min(CHUNK, E - base);
    for (int k = tid * 4; k < cnt; k += 1024) {
        if (k + 3 < cnt) {
            int4 d4 = *(const int4*)(dst + base + k);
            int4 s4 = *(const int4*)(src + base + k);
            atomicAdd(&h[d4.x >> 8], 1); atomicAdd(&h[d4.y >> 8], 1);
            atomicAdd(&h[d4.z >> 8], 1); atomicAdd(&h[d4.w >> 8], 1);
            atomicAdd(&h[NBUK + (s4.x >> 8)], 1); atomicAdd(&h[NBUK + (s4.y >> 8)], 1);
            atomicAdd(&h[NBUK + (s4.z >> 8)], 1); atomicAdd(&h[NBUK + (s4.w >> 8)], 1);
        } else {
            int kend = (k + 4 < cnt) ? k + 4 : cnt;
            for (int t = k; t < kend; ++t) {
                atomicAdd(&h[dst[base + t] >> 8], 1);
                atomicAdd(&h[NBUK + (src[base + t] >> 8)], 1);
            }
        }
    }
    __syncthreads();
    for (int j = tid; j < NBIN; j += 256) per_block[j * PBSTRIDE + blockIdx.x] = h[j];
}

__global__ __launch_bounds__(256) void scanA_kernel(int* __restrict__ per_block,
                                                    int* __restrict__ total, int nblk) {
    int wv = (int)threadIdx.x >> 6;
    int lane = (int)threadIdx.x & 63;
    int j = blockIdx.x * 4 + wv;
    if (j >= NBIN) return;
    int* pb = per_block + (size_t)j * PBSTRIDE;
    int idx = lane * 4;
    int4 v = make_int4(0, 0, 0, 0);
    if (idx + 3 < nblk) {
        v = *(const int4*)(pb + idx);
    } else if (idx < nblk) {
        v.x = pb[idx];
        if (idx + 1 < nblk) v.y = pb[idx + 1];
        if (idx + 2 < nblk) v.z = pb[idx + 2];
    }
    int s1 = v.x + v.y, s2 = s1 + v.z, s3 = s2 + v.w;
    int x = s3;
#pragma unroll
    for (int d = 1; d < 64; d <<= 1) {
        int t = __shfl_up(x, d);
        if (lane >= d) x += t;
    }
    int excl = x - s3;
    int4 r = make_int4(excl, excl + v.x, excl + s1, excl + s2);
    *(int4*)(pb + idx) = r;
    if (lane == 63) total[j] = x;
}

__global__ __launch_bounds__(512) void scanB_kernel(const int* __restrict__ total,
                                                    int* __restrict__ cb_dst,
                                                    int* __restrict__ cb_src,
                                                    float* __restrict__ msum) {
    __shared__ int s[512];
    int tid = (int)threadIdx.x;
    if (tid < D) msum[tid] = 0.0f;
    for (int half = 0; half < 2; ++half) {
        int v = (tid < NBUK) ? total[half * NBUK + tid] : 0;
        s[tid] = v;
        __syncthreads();
        for (int off = 1; off < 512; off <<= 1) {
            int t = (tid >= off) ? s[tid - off] : 0;
            __syncthreads();
            s[tid] += t;
            __syncthreads();
        }
        int* cb = half ? cb_src : cb_dst;
        if (tid < NBUK) cb[tid] = s[tid] - v;
        if (tid == NBUK - 1) cb[NBUK] = s[tid];
        __syncthreads();
    }
}

__global__ __launch_bounds__(256) void phase2_kernel(const int* __restrict__ src,
                                                     const int* __restrict__ dst,
                                                     const int* __restrict__ per_block,
                                                     const int* __restrict__ cb_dst,
                                                     const int* __restrict__ cb_src,
                                                     int* __restrict__ pairs,
                                                     unsigned char* __restrict__ skeys, int E) {
    __shared__ int lcur[NBIN];
    int tid = (int)threadIdx.x;
    for (int j = tid; j < NBIN; j += 256)
        lcur[j] = per_block[(size_t)j * PBSTRIDE + blockIdx.x] +
                  (j < NBUK ? cb_dst[j] : cb_src[j - NBUK]);
    __syncthreads();
    int base = blockIdx.x * CHUNK;
    int cnt = min(CHUNK, E - base);
    for (int k = tid * 4; k < cnt; k += 1024) {
        if (k + 3 < cnt) {
            int4 d4 = *(const int4*)(dst + base + k);
            int4 s4 = *(const int4*)(src + base + k);
            int p;
            p = atomicAdd(&lcur[d4.x >> 8], 1); pairs[p] = (s4.x << 8) | (d4.x & 255);
            p = atomicAdd(&lcur[d4.y >> 8], 1); pairs[p] = (s4.y << 8) | (d4.y & 255);
            p = atomicAdd(&lcur[d4.z >> 8], 1); pairs[p] = (s4.z << 8) | (d4.z & 255);
            p = atomicAdd(&lcur[d4.w >> 8], 1); pairs[p] = (s4.w << 8) | (d4.w & 255);
            p = atomicAdd(&lcur[NBUK + (s4.x >> 8)], 1); skeys[p] = (unsigned char)(s4.x & 255);
            p = atomicAdd(&lcur[NBUK + (s4.y >> 8)], 1); skeys[p] = (unsigned char)(s4.y & 255);
            p = atomicAdd(&lcur[NBUK + (s4.z >> 8)], 1); skeys[p] = (unsigned char)(s4.z & 255);
            p = atomicAdd(&lcur[NBUK + (s4.w >> 8)], 1); skeys[p] = (unsigned char)(s4.w & 255);
        } else {
            int kend = (k + 4 < cnt) ? k + 4 : cnt;
            for (int t = k; t < kend; ++t) {
                int dv = dst[base + t], sv = src[base + t];
                int p = atomicAdd(&lcur[dv >> 8], 1);
                pairs[p] = (sv << 8) | (dv & 255);
                p = atomicAdd(&lcur[NBUK + (sv >> 8)], 1);
                skeys[p] = (unsigned char)(sv & 255);
            }
        }
    }
}

__global__ __launch_bounds__(256) void finalize_csr_kernel(const int* __restrict__ pairs,
                                                           const unsigned char* __restrict__ skeys,
                                                           const int* __restrict__ cb_dst,
                                                           const int* __restrict__ cb_src,
                                                           const float* __restrict__ feat,
                                                           int* __restrict__ row_ptr,
                                                           int* __restrict__ col,
                                                           float* __restrict__ dinv,
                                                           __half* __restrict__ hs, int N) {
    __shared__ int fine[256];
    __shared__ int lcur[256];
    __shared__ float dsh[256];
    __shared__ int wtot[4], wexcl[4];
    int b = (int)blockIdx.x;
    int tid = (int)threadIdx.x, lane = tid & 63, wv = tid >> 6;
    int g = b * 256 + tid;

    fine[tid] = 0;
    __syncthreads();
    int sb0 = cb_src[b], sb1 = cb_src[b + 1];
    for (int i = sb0 + tid; i < sb1; i += 256) atomicAdd(&fine[skeys[i]], 1);
    __syncthreads();
    float dv_ = 1.0f / fmaxf((float)fine[tid], 1.0f);
    dsh[tid] = dv_;
    if (g < N) dinv[g] = dv_;
    __syncthreads();

    {
        int q = tid & 7;
        int rbase = tid >> 3;
        for (int p = 0; p < 8; ++p) {
            int r = p * 32 + rbase;
            int node = b * 256 + r;
            if (node < N) {
                float sc = dsh[r];
                const float4* f = (const float4*)(feat + (size_t)node * D + q * 8);
                float4 v0 = f[0], v1 = f[1];
                __half2 h[4];
                h[0] = __floats2half2_rn(v0.x * sc, v0.y * sc);
                h[1] = __floats2half2_rn(v0.z * sc, v0.w * sc);
                h[2] = __floats2half2_rn(v1.x * sc, v1.y * sc);
                h[3] = __floats2half2_rn(v1.z * sc, v1.w * sc);
                *(float4*)(hs + (size_t)node * D + q * 8) = *(float4*)h;
            }
        }
    }
    __syncthreads();

    fine[tid] = 0;
    __syncthreads();
    int cb0 = cb_dst[b], cb1 = cb_dst[b + 1];
    for (int i = cb0 + tid; i < cb1; i += 256) atomicAdd(&fine[pairs[i] & 255], 1);
    __syncthreads();
    int v = fine[tid], x = v;
#pragma unroll
    for (int d = 1; d < 64; d <<= 1) {
        int t = __shfl_up(x, d);
        if (lane >= d) x += t;
    }
    if (lane == 63) wtot[wv] = x;
    __syncthreads();
    if (tid == 0) {
        int a = 0;
#pragma unroll
        for (int k = 0; k < 4; ++k) { wexcl[k] = a; a += wtot[k]; }
    }
    __syncthreads();
    int excl = x - v + wexcl[wv];
    if (g <= N) row_ptr[g] = cb0 + excl;
    lcur[tid] = cb0 + excl;
    __syncthreads();
    for (int i = cb0 + tid; i < cb1; i += 256) {
        int p = pairs[i];
        int pos = atomicAdd(&lcur[p & 255], 1);
        col[pos] = p >> 8;
    }
}

__device__ inline void accum8(float* a, float4 raw) {
    __half2* h = (__half2*)&raw;
#pragma unroll
    for (int k = 0; k < 4; ++k) {
        float2 f = __half22float2(h[k]);
        a[2 * k] += f.x;
        a[2 * k + 1] += f.y;
    }
}

// ---- fused gather(fp16) + GEMM (+ column-sum on final layer) ----
// R8 = R2's fused verbatim (best measured: 66.7us/layer). Separate kernel
// launches per layer are the COHERENCE FENCE (R7: grid.sync left stale
// cross-XCD L2/L1 lines -> absmax 7.8e-2; kernel boundary flushes).
// Gather: three structurally different pipelines (R0/R1/R2) converged at
// 67+-5us => per-CU miss-concurrency cap (~17-27 lines in flight at ~430cy
// avg L2/L3 latency, Little's law). Don't re-plumb.
// HARD RULE: grid == resident capacity = 768 @ launch_bounds(256,3).
__global__ __launch_bounds__(256, 3) void fused_kernel(const __half* __restrict__ hs_in,
                                                       const int* __restrict__ row_ptr,
                                                       const int* __restrict__ col,
                                                       const float* __restrict__ W,
                                                       const float* __restrict__ bias,
                                                       const float* __restrict__ dinv,
                                                       float* __restrict__ outf,
                                                       __half* __restrict__ outh,
                                                       float* __restrict__ msum,
                                                       int N, int mode) {
    __shared__ int colsh[2][4][384];    // [buf][wave][slot]
    __shared__ float aggT[4][8][68];    // [wave][row][d]
    __shared__ float red[256];
    int tid = (int)threadIdx.x;
    int lane = tid & 63;
    int wv = tid >> 6;
    int sg = lane >> 3;       // row-slot 0..7 within wave
    int q = lane & 7;         // 8 lanes per row, 16B (8 halves) each
    int g = wv * 8 + sg;      // block row 0..31

    float Wreg[64];
#pragma unroll
    for (int k = 0; k < 64; ++k) Wreg[k] = W[k * 64 + lane];
    float breg = bias[lane];
    float colacc = 0.0f;

    int ntiles = (N + 31) >> 5;
    int tile = (int)blockIdx.x;

    int beg, deg, off, cnt;
    {
        int node = tile * 32 + g;
        beg = row_ptr[min(node, N)];
        int end = row_ptr[min(node + 1, N)];
        int cb = __shfl(beg, 0);        // lane 0: sg=0,q=0 -> row_ptr[wfirst]
        int ce = __shfl(end, 56);       // lane 56: sg=7 -> row_ptr[wfirst+8]
        cnt = ce - cb; off = beg - cb; deg = end - beg;
        if (cnt <= 384) {
#pragma unroll
            for (int k = 0; k < 6; ++k) {
                int i = k * 64 + lane;
                if (i < cnt) colsh[0][wv][i] = col[cb + i];
            }
        }
    }
    int p = 0;

    while (tile < ntiles) {
        int md = deg;                  // wave-max degree (groups on lane bits 3..5)
        md = max(md, __shfl_xor(md, 8));
        md = max(md, __shfl_xor(md, 16));
        md = max(md, __shfl_xor(md, 32));
        int rounds = (md + 3) >> 2;

        float a[8];
#pragma unroll
        for (int k = 0; k < 8; ++k) a[k] = 0.0f;

        if (cnt <= 384) {
            const int* cbuf = &colsh[p][wv][0];
            int cl = cnt - 1;          // clamp: overflow lanes dup a valid col -> L1-hit
            float4 A0, A1, A2, A3, B0, B1, B2, B3;
#define LD1(dstv, e_) { int ci = min(off + (e_), cl); int srcn = cbuf[ci]; \
                        dstv = *(const float4*)(hs_in + (size_t)srcn * D + q * 8); }
#define ISS(X0, X1, X2, X3, b_) { int eb = (b_) << 2; \
        LD1(X0, eb) LD1(X1, eb + 1) LD1(X2, eb + 2) LD1(X3, eb + 3) }
#define CNS(X0, X1, X2, X3, b_) { int eb = (b_) << 2; \
        if (eb < deg) accum8(a, X0); if (eb + 1 < deg) accum8(a, X1); \
        if (eb + 2 < deg) accum8(a, X2); if (eb + 3 < deg) accum8(a, X3); }
            if (rounds > 0) {
                ISS(A0, A1, A2, A3, 0)
                if (rounds > 1) ISS(B0, B1, B2, B3, 1)
                int b = 0;
                while (true) {
                    CNS(A0, A1, A2, A3, b)
                    if (b + 2 < rounds) ISS(A0, A1, A2, A3, b + 2)
                    ++b; if (b >= rounds) break;
                    CNS(B0, B1, B2, B3, b)
                    if (b + 2 < rounds) ISS(B0, B1, B2, B3, b + 2)
                    ++b; if (b >= rounds) break;
                }
            }
#undef LD1
#undef ISS
#undef CNS
        } else {
            int end = beg + deg;
            for (int j = beg; j < end; ++j) {
                int s0 = col[j];
                float4 r0 = *(const float4*)(hs_in + (size_t)s0 * D + q * 8);
                accum8(a, r0);
            }
        }

        // ---- prefetch next tile: meta + col values into REGS (loads issue
        //      here, dependent ds_writes land AFTER the GEMM) ----
        int tile2 = tile + (int)gridDim.x;
        bool hn = tile2 < ntiles;
        int beg2 = 0, deg2 = 0, off2 = 0, cnt2 = 0, cb2 = 0;
        if (hn) {
            int node2 = tile2 * 32 + g;
            beg2 = row_ptr[min(node2, N)];
            int end2 = row_ptr[min(node2 + 1, N)];
            cb2 = __shfl(beg2, 0);
            int ce2 = __shfl(end2, 56);
            cnt2 = ce2 - cb2; off2 = beg2 - cb2; deg2 = end2 - beg2;
        }
        int stg[6];
        bool sv[6];
#pragma unroll
        for (int k = 0; k < 6; ++k) {
            int i = k * 64 + lane;
            sv[k] = hn && cnt2 <= 384 && i < cnt2;
            stg[k] = sv[k] ? col[cb2 + i] : 0;
        }

        // ---- aggT + GEMM (wave-private rows; lgkm ordering only) ----
        *(float4*)(&aggT[wv][sg][q * 8]) = make_float4(a[0], a[1], a[2], a[3]);
        *(float4*)(&aggT[wv][sg][q * 8 + 4]) = make_float4(a[4], a[5], a[6], a[7]);

#pragma unroll
        for (int rr = 0; rr < 8; ++rr) {
            int node = tile * 32 + wv * 8 + rr;
            if (node < N) {
                float acc0 = breg, acc1 = 0.0f;
                const float4* Ar = (const float4*)(&aggT[wv][rr][0]);
#pragma unroll
                for (int k4 = 0; k4 < 16; k4 += 2) {
                    float4 av0 = Ar[k4];       // broadcast ds_read_b128, same-wave data
                    float4 av1 = Ar[k4 + 1];
                    acc0 = fmaf(av0.x, Wreg[k4 * 4 + 0], acc0);
                    acc0 = fmaf(av0.y, Wreg[k4 * 4 + 1], acc0);
                    acc0 = fmaf(av0.z, Wreg[k4 * 4 + 2], acc0);
                    acc0 = fmaf(av0.w, Wreg[k4 * 4 + 3], acc0);
                    acc1 = fmaf(av1.x, Wreg[k4 * 4 + 4], acc1);
                    acc1 = fmaf(av1.y, Wreg[k4 * 4 + 5], acc1);
                    acc1 = fmaf(av1.z, Wreg[k4 * 4 + 6], acc1);
                    acc1 = fmaf(av1.w, Wreg[k4 * 4 + 7], acc1);
                }
                float acc = acc0 + acc1;
                if (mode == 0) {
                    acc = fmaxf(acc, 0.0f) * dinv[node];
                    outh[(size_t)node * D + lane] = __float2half(acc);
                } else {
                    colacc += acc;
                    outf[(size_t)node * D + lane] = acc;
                }
            }
        }

        // ---- commit staged col values (vmcnt waits hidden under the GEMM) ----
#pragma unroll
        for (int k = 0; k < 6; ++k)
            if (sv[k]) colsh[p ^ 1][wv][k * 64 + lane] = stg[k];

        p ^= 1;
        tile = tile2;
        beg = beg2; deg = deg2; off = off2; cnt = cnt2;
    }

    if (mode == 1) {
        red[tid] = colacc;
        __syncthreads();
        if (wv == 0) {
            float s = red[lane] + red[64 + lane] + red[128 + lane] + red[192 + lane];
            atomicAdd(&msum[lane], s);
        }
    }
}

__global__ void finalize_kernel(const float* __restrict__ msum, float* __restrict__ outMean,
                                float invN) {
    outMean[threadIdx.x] = msum[threadIdx.x] * invN;
}

extern "C" void kernel_launch(void* const* d_in, const int* in_sizes, int n_in,
                              void* d_out, int out_size, void* d_ws, size_t ws_size,
                              hipStream_t stream) {
    const float* feat = (const float*)d_in[0];
    const int* src = (const int*)d_in[1];
    const int* dst = (const int*)d_in[2];
    const float* W0 = (const float*)d_in[3];
    const float* b0 = (const float*)d_in[4];
    const float* W1 = (const float*)d_in[5];
    const float* b1 = (const float*)d_in[6];
    const float* W2 = (const float*)d_in[7];
    const float* b2 = (const float*)d_in[8];

    const int N = in_sizes[0] / D;  // 100000
    const int E = in_sizes[1];      // 1600000
    float* out = (float*)d_out;     // [N*D + D] floats

    const int NBLK = (E + CHUNK - 1) / CHUNK;  // 256 == PBSTRIDE (1 block/CU)

    // workspace layout (int units), 16B-aligned offsets; NA = padded N+1
    int* wsi = (int*)d_ws;
    const size_t NA = 100352;
    int*   row_ptr  = wsi;                       // NA
    float* dinv     = (float*)(wsi + NA);        // NA
    float* msum     = (float*)(wsi + 2 * NA);    // 64 (pad 256)
    int*   total    = wsi + 2 * NA + 256;        // 782 (pad 1024)
    int*   cb_dst   = wsi + 2 * NA + 1280;       // 392 (pad 512)
    int*   cb_src   = wsi + 2 * NA + 1792;       // 392 (pad 512)
    int*   per_blk  = wsi + 2 * NA + 2304;       // NBIN*PBSTRIDE = 200192 (pad 200704)
    int*   pairs    = wsi + 2 * NA + 203008;     // E
    unsigned char* skeys = (unsigned char*)(pairs + (size_t)E);  // E bytes (pad -> 400000 ints)
    int*   col      = pairs + (size_t)E + 400000;                // E
    __half* hsA     = (__half*)(col + (size_t)E);                // N*D halves
    __half* hsB     = hsA + (size_t)N * D;                       // N*D halves

    phase1_kernel<<<NBLK, 256, 0, stream>>>(src, dst, per_blk, E);
    scanA_kernel<<<(NBIN + 3) / 4, 256, 0, stream>>>(per_blk, total, NBLK);
    scanB_kernel<<<1, 512, 0, stream>>>(total, cb_dst, cb_src, msum);
    phase2_kernel<<<NBLK, 256, 0, stream>>>(src, dst, per_blk, cb_dst, cb_src, pairs, skeys, E);
    finalize_csr_kernel<<<NBUK, 256, 0, stream>>>(pairs, skeys, cb_dst, cb_src, feat,
                                                  row_ptr, col, dinv, hsA, N);

    const int FG = 768;   // == resident capacity at 3 waves/SIMD (launch_bounds(256,3))
    fused_kernel<<<FG, 256, 0, stream>>>(hsA, row_ptr, col, W0, b0, dinv, nullptr, hsB, msum, N, 0);
    fused_kernel<<<FG, 256, 0, stream>>>(hsB, row_ptr, col, W1, b1, dinv, nullptr, hsA, msum, N, 0);
    fused_kernel<<<FG, 256, 0, stream>>>(hsA, row_ptr, col, W2, b2, dinv, out, nullptr, msum, N, 1);

    finalize_kernel<<<1, 64, 0, stream>>>(msum, out + (size_t)N * D, 1.0f / (float)N);
}